// Round 1
// baseline (537.770 us; speedup 1.0000x reference)
//
#include <hip/hip_runtime.h>

// Problem constants (from reference setup_inputs)
#define IMGS 8
#define HH 240
#define WW 320
#define CC 128          // channels
#define HW (HH * WW)    // 76800 pixels per image

// ---------------------------------------------------------------------------
// Kernel 1: gather image feats at point pixels, mean over images per point.
// 32 lanes per point, each lane handles a float4 (4 channels). Block 256 = 8 pts.
// ---------------------------------------------------------------------------
__global__ __launch_bounds__(256) void gather_kernel(
    const float* __restrict__ img,   // [I, H, W, C]
    const int*   __restrict__ pix,   // [I, N, 2]
    float*       __restrict__ out,   // [N, C]
    int N)
{
    int tid   = blockIdx.x * blockDim.x + threadIdx.x;
    int point = tid >> 5;
    int lane  = tid & 31;
    if (point >= N) return;

    float4 acc = make_float4(0.f, 0.f, 0.f, 0.f);
    float  cnt = 0.f;
#pragma unroll
    for (int i = 0; i < IMGS; ++i) {
        int2 hw = *reinterpret_cast<const int2*>(pix + ((size_t)i * N + point) * 2);
        int h = hw.x, w = hw.y;
        if (h >= 0 && h < HH && w >= 0 && w < WW) {
            const float4* row = reinterpret_cast<const float4*>(
                img + ((size_t)i * HW + (size_t)h * WW + w) * CC);
            float4 v = row[lane];
            acc.x += v.x; acc.y += v.y; acc.z += v.z; acc.w += v.w;
            cnt += 1.f;
        }
    }
    float inv = 1.f / fmaxf(cnt, 1e-10f);
    acc.x *= inv; acc.y *= inv; acc.z *= inv; acc.w *= inv;
    reinterpret_cast<float4*>(out + (size_t)point * CC)[lane] = acc;
}

// ---------------------------------------------------------------------------
// Kernel 2: scatter point feats into image grid (atomic sum + count).
// 128 threads per (i,n) pair -> 1 channel each. Block 256 = 2 pairs.
// grid = (ceil(N/2), I)
// ---------------------------------------------------------------------------
__global__ __launch_bounds__(256) void scatter_kernel(
    const float* __restrict__ pcd,      // [N, C]
    const int*   __restrict__ pix,      // [I, N, 2]
    float*       __restrict__ img_sum,  // [I, H, W, C] (pre-zeroed)
    float*       __restrict__ cnt,      // [I, H, W]    (pre-zeroed)
    int N)
{
    int n = blockIdx.x * 2 + (threadIdx.x >> 7);
    int c = threadIdx.x & 127;
    int i = blockIdx.y;
    if (n >= N) return;

    int2 hw = *reinterpret_cast<const int2*>(pix + ((size_t)i * N + n) * 2);
    int h = hw.x, w = hw.y;
    if (h >= 0 && h < HH && w >= 0 && w < WW) {
        size_t p = (size_t)i * HW + (size_t)h * WW + w;
        atomicAdd(&img_sum[p * CC + c], pcd[(size_t)n * CC + c]);
        if (c == 0) atomicAdd(&cnt[p], 1.f);
    }
}

// ---------------------------------------------------------------------------
// Kernel 3: in-place normalize img_sum by counts.
// 32 lanes per pixel, float4 per lane. Block 256 = 8 pixels.
// ---------------------------------------------------------------------------
__global__ __launch_bounds__(256) void normalize_kernel(
    float*       __restrict__ img_sum,  // [I*H*W, C]
    const float* __restrict__ cnt)      // [I*H*W]
{
    int tid  = blockIdx.x * blockDim.x + threadIdx.x;
    int pixI = tid >> 5;
    int lane = tid & 31;
    const int total = IMGS * HW;
    if (pixI >= total) return;

    float inv = 1.f / fmaxf(cnt[pixI], 1e-10f);
    float4* p = reinterpret_cast<float4*>(img_sum + (size_t)pixI * CC);
    float4 v = p[lane];
    v.x *= inv; v.y *= inv; v.z *= inv; v.w *= inv;
    p[lane] = v;
}

extern "C" void kernel_launch(void* const* d_in, const int* in_sizes, int n_in,
                              void* d_out, int out_size, void* d_ws, size_t ws_size,
                              hipStream_t stream)
{
    const float* img_feats  = (const float*)d_in[0];
    const float* pcd_feats  = (const float*)d_in[1];
    const int*   pcd_pixels = (const int*)d_in[2];

    const int N = in_sizes[1] / CC;   // pcd_feats is [N, C]

    float* out_pcd = (float*)d_out;                     // [N, C]
    float* out_img = out_pcd + (size_t)N * CC;          // [I, H, W, C]
    float* cnt     = (float*)d_ws;                      // [I*H*W] floats

    // Zero accumulation targets every call (harness does not re-poison/zero).
    hipMemsetAsync(out_img, 0, (size_t)IMGS * HW * CC * sizeof(float), stream);
    hipMemsetAsync(cnt,     0, (size_t)IMGS * HW * sizeof(float), stream);

    // Gather: N points * 32 lanes
    {
        int threads = 256;
        int blocks  = (N * 32 + threads - 1) / threads;
        gather_kernel<<<blocks, threads, 0, stream>>>(img_feats, pcd_pixels, out_pcd, N);
    }

    // Scatter: (I, N) pairs * 128 threads
    {
        dim3 block(256, 1, 1);
        dim3 grid((N + 1) / 2, IMGS, 1);
        scatter_kernel<<<grid, block, 0, stream>>>(pcd_feats, pcd_pixels, out_img, cnt, N);
    }

    // Normalize: I*H*W pixels * 32 lanes
    {
        int threads = 256;
        long long t = (long long)IMGS * HW * 32;
        int blocks  = (int)((t + threads - 1) / threads);
        normalize_kernel<<<blocks, threads, 0, stream>>>(out_img, cnt);
    }
}

// Round 2
// 254.493 us; speedup vs baseline: 2.1131x; 2.1131x over previous
//
#include <hip/hip_runtime.h>

// Problem constants (from reference setup_inputs)
#define IMGS 8
#define HH 240
#define WW 320
#define CC 128          // channels
#define HW (HH * WW)    // 76800 pixels per image
#define ELEMS (IMGS * HW) // 614400 pixel slots total
#define SCAN_BLK 1024
#define NBLOCKS (ELEMS / SCAN_BLK)  // 600, exact

// ---------------------------------------------------------------------------
// Kernel 1: gather image feats at point pixels, mean over images per point.
// 32 lanes per point, each lane a float4. Block 256 = 8 points.
// ---------------------------------------------------------------------------
__global__ __launch_bounds__(256) void gather_kernel(
    const float* __restrict__ img,   // [I, H, W, C]
    const int*   __restrict__ pix,   // [I, N, 2]
    float*       __restrict__ out,   // [N, C]
    int N)
{
    int tid   = blockIdx.x * blockDim.x + threadIdx.x;
    int point = tid >> 5;
    int lane  = tid & 31;
    if (point >= N) return;

    float4 acc = make_float4(0.f, 0.f, 0.f, 0.f);
    float  cnt = 0.f;
#pragma unroll
    for (int i = 0; i < IMGS; ++i) {
        int2 hw = *reinterpret_cast<const int2*>(pix + ((size_t)i * N + point) * 2);
        int h = hw.x, w = hw.y;
        if (h >= 0 && h < HH && w >= 0 && w < WW) {
            const float4* row = reinterpret_cast<const float4*>(
                img + ((size_t)i * HW + (size_t)h * WW + w) * CC);
            float4 v = row[lane];
            acc.x += v.x; acc.y += v.y; acc.z += v.z; acc.w += v.w;
            cnt += 1.f;
        }
    }
    float inv = 1.f / fmaxf(cnt, 1e-10f);
    acc.x *= inv; acc.y *= inv; acc.z *= inv; acc.w *= inv;
    reinterpret_cast<float4*>(out + (size_t)point * CC)[lane] = acc;
}

// ---------------------------------------------------------------------------
// CSR build: count per-pixel points. grid = (ceil(N/256), I)
// ---------------------------------------------------------------------------
__global__ __launch_bounds__(256) void count_kernel(
    const int* __restrict__ pix,      // [I, N, 2]
    unsigned*  __restrict__ counts,   // [ELEMS] (pre-zeroed)
    int N)
{
    int n = blockIdx.x * 256 + threadIdx.x;
    int i = blockIdx.y;
    if (n >= N) return;
    int2 hw = *reinterpret_cast<const int2*>(pix + ((size_t)i * N + n) * 2);
    int h = hw.x, w = hw.y;
    if (h >= 0 && h < HH && w >= 0 && w < WW) {
        atomicAdd(&counts[i * HW + h * WW + w], 1u);
    }
}

// ---------------------------------------------------------------------------
// Scan stage 1: per-block (1024-elem) sums. grid = NBLOCKS, block = 1024.
// ---------------------------------------------------------------------------
__global__ __launch_bounds__(SCAN_BLK) void scan1_kernel(
    const unsigned* __restrict__ counts,
    unsigned*       __restrict__ blocksums)   // [NBLOCKS]
{
    __shared__ unsigned lds[SCAN_BLK];
    int t = threadIdx.x;
    lds[t] = counts[blockIdx.x * SCAN_BLK + t];
    __syncthreads();
    for (int off = SCAN_BLK / 2; off > 0; off >>= 1) {
        if (t < off) lds[t] += lds[t + off];
        __syncthreads();
    }
    if (t == 0) blocksums[blockIdx.x] = lds[0];
}

// ---------------------------------------------------------------------------
// Scan stage 2: exclusive scan of blocksums (NBLOCKS<=1024). 1 block of 1024.
// ---------------------------------------------------------------------------
__global__ __launch_bounds__(SCAN_BLK) void scan2_kernel(
    unsigned* __restrict__ blocksums, int nb)
{
    __shared__ unsigned lds[SCAN_BLK];
    int t = threadIdx.x;
    unsigned own = (t < nb) ? blocksums[t] : 0u;
    lds[t] = own;
    __syncthreads();
    for (int off = 1; off < SCAN_BLK; off <<= 1) {
        unsigned v = (t >= off) ? lds[t - off] : 0u;
        __syncthreads();
        lds[t] += v;
        __syncthreads();
    }
    if (t < nb) blocksums[t] = lds[t] - own;  // exclusive
}

// ---------------------------------------------------------------------------
// Scan stage 3: per-block exclusive scan + block base -> offsets.
// ---------------------------------------------------------------------------
__global__ __launch_bounds__(SCAN_BLK) void scan3_kernel(
    const unsigned* __restrict__ counts,
    const unsigned* __restrict__ blocksums,
    unsigned*       __restrict__ offsets)     // [ELEMS]
{
    __shared__ unsigned lds[SCAN_BLK];
    int t = threadIdx.x;
    int g = blockIdx.x * SCAN_BLK + t;
    unsigned own = counts[g];
    lds[t] = own;
    __syncthreads();
    for (int off = 1; off < SCAN_BLK; off <<= 1) {
        unsigned v = (t >= off) ? lds[t - off] : 0u;
        __syncthreads();
        lds[t] += v;
        __syncthreads();
    }
    offsets[g] = blocksums[blockIdx.x] + lds[t] - own;  // exclusive
}

// ---------------------------------------------------------------------------
// Fill: scatter point index n into its pixel's CSR segment.
// Uses offsets[] as cursors; afterwards offsets[p] == original offsets[p+1].
// grid = (ceil(N/256), I)
// ---------------------------------------------------------------------------
__global__ __launch_bounds__(256) void fill_kernel(
    const int* __restrict__ pix,      // [I, N, 2]
    unsigned*  __restrict__ offsets,  // [ELEMS] cursors
    unsigned*  __restrict__ list,     // [I*N] point indices
    int N)
{
    int n = blockIdx.x * 256 + threadIdx.x;
    int i = blockIdx.y;
    if (n >= N) return;
    int2 hw = *reinterpret_cast<const int2*>(pix + ((size_t)i * N + n) * 2);
    int h = hw.x, w = hw.y;
    if (h >= 0 && h < HH && w >= 0 && w < WW) {
        unsigned slot = atomicAdd(&offsets[i * HW + h * WW + w], 1u);
        list[slot] = (unsigned)n;
    }
}

// ---------------------------------------------------------------------------
// Output: per pixel, sum its points' feature rows, divide by count, write once.
// Empty pixels write zeros (subsumes the memset). 32 lanes/pixel, block 256.
// After fill, segment for pixel p is [p==0 ? 0 : offsets[p-1], +counts[p]).
// ---------------------------------------------------------------------------
__global__ __launch_bounds__(256) void output_kernel(
    const float*    __restrict__ pcd,      // [N, C]
    const unsigned* __restrict__ counts,   // [ELEMS]
    const unsigned* __restrict__ offsets,  // [ELEMS] (post-fill cursors)
    const unsigned* __restrict__ list,     // [I*N]
    float*          __restrict__ out_img)  // [ELEMS, C]
{
    int tid  = blockIdx.x * blockDim.x + threadIdx.x;
    int p    = tid >> 5;
    int lane = tid & 31;
    if (p >= ELEMS) return;

    unsigned k     = counts[p];
    unsigned start = (p == 0) ? 0u : offsets[p - 1];

    float4 acc = make_float4(0.f, 0.f, 0.f, 0.f);
    for (unsigned j = start; j < start + k; ++j) {
        unsigned idx = list[j];
        float4 v = reinterpret_cast<const float4*>(pcd + (size_t)idx * CC)[lane];
        acc.x += v.x; acc.y += v.y; acc.z += v.z; acc.w += v.w;
    }
    float inv = 1.f / fmaxf((float)k, 1e-10f);
    acc.x *= inv; acc.y *= inv; acc.z *= inv; acc.w *= inv;
    reinterpret_cast<float4*>(out_img + (size_t)p * CC)[lane] = acc;
}

// ---------------------------------------------------------------------------
// Fallback path (atomic scatter), used only if ws_size is too small for CSR.
// ---------------------------------------------------------------------------
__global__ __launch_bounds__(256) void scatter_kernel(
    const float* __restrict__ pcd, const int* __restrict__ pix,
    float* __restrict__ img_sum, float* __restrict__ cnt, int N)
{
    int n = blockIdx.x * 2 + (threadIdx.x >> 7);
    int c = threadIdx.x & 127;
    int i = blockIdx.y;
    if (n >= N) return;
    int2 hw = *reinterpret_cast<const int2*>(pix + ((size_t)i * N + n) * 2);
    int h = hw.x, w = hw.y;
    if (h >= 0 && h < HH && w >= 0 && w < WW) {
        size_t p = (size_t)i * HW + (size_t)h * WW + w;
        atomicAdd(&img_sum[p * CC + c], pcd[(size_t)n * CC + c]);
        if (c == 0) atomicAdd(&cnt[p], 1.f);
    }
}

__global__ __launch_bounds__(256) void normalize_kernel(
    float* __restrict__ img_sum, const float* __restrict__ cnt)
{
    int tid  = blockIdx.x * blockDim.x + threadIdx.x;
    int pixI = tid >> 5;
    int lane = tid & 31;
    if (pixI >= ELEMS) return;
    float inv = 1.f / fmaxf(cnt[pixI], 1e-10f);
    float4* p = reinterpret_cast<float4*>(img_sum + (size_t)pixI * CC);
    float4 v = p[lane];
    v.x *= inv; v.y *= inv; v.z *= inv; v.w *= inv;
    p[lane] = v;
}

extern "C" void kernel_launch(void* const* d_in, const int* in_sizes, int n_in,
                              void* d_out, int out_size, void* d_ws, size_t ws_size,
                              hipStream_t stream)
{
    const float* img_feats  = (const float*)d_in[0];
    const float* pcd_feats  = (const float*)d_in[1];
    const int*   pcd_pixels = (const int*)d_in[2];

    const int N     = in_sizes[1] / CC;   // pcd_feats is [N, C]
    const int PAIRS = IMGS * N;

    float* out_pcd = (float*)d_out;                     // [N, C]
    float* out_img = out_pcd + (size_t)N * CC;          // [I, H, W, C]

    // Gather side (same in both paths)
    {
        int threads = 256;
        int blocks  = (N * 32 + threads - 1) / threads;
        gather_kernel<<<blocks, threads, 0, stream>>>(img_feats, pcd_pixels, out_pcd, N);
    }

    // Workspace layout for CSR path
    size_t need = (size_t)ELEMS * 4      // counts
                + (size_t)ELEMS * 4      // offsets
                + (size_t)SCAN_BLK * 4   // blocksums (padded)
                + (size_t)PAIRS * 4;     // list

    if (ws_size >= need) {
        unsigned* counts    = (unsigned*)d_ws;
        unsigned* offsets   = counts + ELEMS;
        unsigned* blocksums = offsets + ELEMS;
        unsigned* list      = blocksums + SCAN_BLK;

        hipMemsetAsync(counts, 0, (size_t)ELEMS * 4, stream);

        dim3 pgrid((N + 255) / 256, IMGS, 1);
        count_kernel<<<pgrid, 256, 0, stream>>>(pcd_pixels, counts, N);
        scan1_kernel<<<NBLOCKS, SCAN_BLK, 0, stream>>>(counts, blocksums);
        scan2_kernel<<<1, SCAN_BLK, 0, stream>>>(blocksums, NBLOCKS);
        scan3_kernel<<<NBLOCKS, SCAN_BLK, 0, stream>>>(counts, blocksums, offsets);
        fill_kernel<<<pgrid, 256, 0, stream>>>(pcd_pixels, offsets, list, N);

        int blocks = (ELEMS * 32) / 256;  // 76800
        output_kernel<<<blocks, 256, 0, stream>>>(pcd_feats, counts, offsets, list, out_img);
    } else {
        // Fallback: atomic scatter (round-1 path)
        float* cnt = (float*)d_ws;
        hipMemsetAsync(out_img, 0, (size_t)ELEMS * CC * sizeof(float), stream);
        hipMemsetAsync(cnt,     0, (size_t)ELEMS * sizeof(float), stream);
        dim3 sgrid((N + 1) / 2, IMGS, 1);
        scatter_kernel<<<sgrid, 256, 0, stream>>>(pcd_feats, pcd_pixels, out_img, cnt, N);
        long long t = (long long)ELEMS * 32;
        int blocks  = (int)((t + 255) / 256);
        normalize_kernel<<<blocks, 256, 0, stream>>>(out_img, cnt);
    }
}